// Round 3
// baseline (651.352 us; speedup 1.0000x reference)
//
#include <hip/hip_runtime.h>

#define CIN  64
#define COUT 64

typedef __attribute__((ext_vector_type(8))) short bf16x8;
typedef __attribute__((ext_vector_type(4))) float f32x4;
typedef __attribute__((ext_vector_type(2))) float f32x2;

// round-to-nearest-even f32 -> bf16
__device__ inline unsigned short f2bf(float f) {
    unsigned u = __float_as_uint(f);
    return (unsigned short)((u + 0x7FFFu + ((u >> 16) & 1u)) >> 16);
}

// 64-bit packed fp32 atomic add (global_atomic_pk_add_f32). Halves the
// atomic-op count vs two scalar adds. Fallback keeps it compiling anywhere.
__device__ inline void atomic_pk_add(float* addr, f32x2 v) {
#if __has_builtin(__builtin_amdgcn_global_atomic_fadd_v2f32)
    typedef __attribute__((address_space(1))) f32x2 gf32x2;
    __builtin_amdgcn_global_atomic_fadd_v2f32(
        (gf32x2*)(unsigned long long)(void*)addr, v);
#else
    atomicAdd(addr + 0, v.x);
    atomicAdd(addr + 1, v.y);
#endif
}

// Implicit-GEMM sparse conv, MFMA compute + packed-atomic scatter.
// One wave = 16 pairs/iter, v_mfma_f32_16x16x32_bf16, W[k] register-resident.
__global__ __launch_bounds__(256)
void spconv_mfma(const float* __restrict__ feats,
                 const float* __restrict__ weight,
                 const int*   __restrict__ in_map,
                 const int*   __restrict__ out_map,
                 float*       __restrict__ out,
                 int M) {
    const int k     = blockIdx.y;
    const int tid   = threadIdx.x;
    const int lane  = tid & 63;
    const int m     = lane & 15;   // A-row / B-col / C-col index
    const int quad  = lane >> 4;
    const int wave  = blockIdx.x * 4 + (tid >> 6);
    const int nwaves = gridDim.x * 4;

    // ---- Preload B fragments: b[t][h][j] = W[k][c][n],
    //      c = 32*h + 8*quad + j, n = 16*t + m ----
    const float* __restrict__ wk = weight + (size_t)k * (CIN * COUT);
    bf16x8 bfrag[4][2];
#pragma unroll
    for (int t = 0; t < 4; ++t) {
#pragma unroll
        for (int h = 0; h < 2; ++h) {
            const int n = 16 * t + m;
            const int c0 = 32 * h + 8 * quad;
#pragma unroll
            for (int j = 0; j < 8; ++j)
                bfrag[t][h][j] = (short)f2bf(wk[(c0 + j) * COUT + n]);
        }
    }

    const int base   = k * M;
    const int ntiles = M >> 4;      // 3125

    for (int tile = wave; tile < ntiles; tile += nwaves) {
        const int p0 = tile << 4;

        const int in_row  = in_map[base + p0 + m];
        const int out_row = out_map[base + p0 + m];

        // ---- Gather A: lane holds channels [8*quad + 32*h, +8) of row m ----
        const float* __restrict__ fr = feats + (size_t)in_row * CIN + 8 * quad;
        const f32x4 f0 = *(const f32x4*)(fr + 0);
        const f32x4 f1 = *(const f32x4*)(fr + 4);
        const f32x4 f2 = *(const f32x4*)(fr + 32);
        const f32x4 f3 = *(const f32x4*)(fr + 36);

        bf16x8 a0, a1;
#pragma unroll
        for (int j = 0; j < 4; ++j) {
            a0[j]     = (short)f2bf(f0[j]);
            a0[j + 4] = (short)f2bf(f1[j]);
            a1[j]     = (short)f2bf(f2[j]);
            a1[j + 4] = (short)f2bf(f3[j]);
        }

        // out rows this lane's C registers belong to (rows 4*quad + r)
        int orow[4];
#pragma unroll
        for (int r = 0; r < 4; ++r)
            orow[r] = __shfl(out_row, 4 * quad + r);

        // ---- MFMA: 4 col-tiles x 2 K-halves ----
        f32x4 acc[4];
#pragma unroll
        for (int t = 0; t < 4; ++t) {
            acc[t] = {0.f, 0.f, 0.f, 0.f};
            acc[t] = __builtin_amdgcn_mfma_f32_16x16x32_bf16(a0, bfrag[t][0], acc[t], 0, 0, 0);
            acc[t] = __builtin_amdgcn_mfma_f32_16x16x32_bf16(a1, bfrag[t][1], acc[t], 0, 0, 0);
        }

        // ---- Scatter with packed 2xf32 atomics ----
        // C layout: lane (quad,m) holds C[4q+r][16t+m]. Lanes l and l^1 share
        // rows and hold adjacent cols -> exchange via shfl_xor(1), then even
        // lane writes rows 4q+0/1, odd lane rows 4q+2/3, both cols at once.
        const bool odd = (m & 1);
#pragma unroll
        for (int t = 0; t < 4; ++t) {
            const float pv0 = __shfl_xor(acc[t][0], 1);
            const float pv1 = __shfl_xor(acc[t][1], 1);
            const float pv2 = __shfl_xor(acc[t][2], 1);
            const float pv3 = __shfl_xor(acc[t][3], 1);
            const int colb = 16 * t + (m & ~1);

            const int ra = odd ? orow[2] : orow[0];
            const int rb = odd ? orow[3] : orow[1];
            f32x2 va, vb;
            va.x = odd ? pv2       : acc[t][0];
            va.y = odd ? acc[t][2] : pv0;
            vb.x = odd ? pv3       : acc[t][1];
            vb.y = odd ? acc[t][3] : pv1;

            atomic_pk_add(out + (size_t)ra * COUT + colb, va);
            atomic_pk_add(out + (size_t)rb * COUT + colb, vb);
        }
    }
}

extern "C" void kernel_launch(void* const* d_in, const int* in_sizes, int n_in,
                              void* d_out, int out_size, void* d_ws, size_t ws_size,
                              hipStream_t stream) {
    const float* feats   = (const float*)d_in[0];
    const float* weight  = (const float*)d_in[1];
    const int*   in_map  = (const int*)d_in[2];
    const int*   out_map = (const int*)d_in[3];
    float*       out     = (float*)d_out;

    const int K = in_sizes[1] / (CIN * COUT);   // 27
    const int M = in_sizes[2] / K;              // 50000

    // d_out is re-poisoned before every timed launch -> zero it (async memset
    // is graph-capture safe; fp32 zero == all-zero bytes).
    hipMemsetAsync(out, 0, (size_t)out_size * sizeof(float), stream);

    // 80 blocks x 4 waves per k ~= fills the 8192 wave slots.
    dim3 grid(80, K);
    spconv_mfma<<<grid, 256, 0, stream>>>(feats, weight, in_map, out_map, out, M);
}

// Round 4
// 510.184 us; speedup vs baseline: 1.2767x; 1.2767x over previous
//
#include <hip/hip_runtime.h>
#include <hip/hip_fp16.h>

#define CIN  64
#define COUT 64
#define CAP  48   // per-out-row bucket capacity; counts ~Poisson(6.75), P(>=48)~e^-90

typedef __attribute__((ext_vector_type(8))) short bf16x8;
typedef __attribute__((ext_vector_type(4))) float f32x4;

// round-to-nearest-even f32 -> bf16
__device__ inline unsigned short f2bf(float f) {
    unsigned u = __float_as_uint(f);
    return (unsigned short)((u + 0x7FFFu + ((u >> 16) & 1u)) >> 16);
}

// ---------------------------------------------------------------------------
// Build inverse rulebook: for each out row, list of global pair ids g=k*M+p.
// Fixed-capacity buckets, no sort/scan. cnt[] must be pre-zeroed.
// ---------------------------------------------------------------------------
__global__ __launch_bounds__(256)
void build_inverse(const int* __restrict__ out_map, int total,
                   int* __restrict__ cnt, int* __restrict__ pairlist) {
    int g = blockIdx.x * 256 + threadIdx.x;
    if (g >= total) return;
    int r = out_map[g];
    int pos = atomicAdd(&cnt[r], 1);
    if (pos < CAP) pairlist[r * CAP + pos] = g;
}

// ---------------------------------------------------------------------------
// Phase 1: implicit-GEMM (MFMA) producing partial[g][64] in fp16, stored in
// C-fragment-native layout: for global tile T (=g>>4), within-tile row
// r'=g&15 at element offset T*1024 + 256*(r'>>2) + 64*(r'&3), cols 0..63
// contiguous. No atomics, pure streaming stores.
// ---------------------------------------------------------------------------
__global__ __launch_bounds__(256)
void spconv_phase1(const float* __restrict__ feats,
                   const float* __restrict__ weight,
                   const int*   __restrict__ in_map,
                   __half*      __restrict__ partial,
                   int M) {
    const int k      = blockIdx.y;
    const int tid    = threadIdx.x;
    const int lane   = tid & 63;
    const int m      = lane & 15;
    const int quad   = lane >> 4;
    const int wave   = blockIdx.x * 4 + (tid >> 6);
    const int nwaves = gridDim.x * 4;

    // Preload B fragments: b[t][h][j] = W[k][32h+8q+j][16t+m]
    const float* __restrict__ wk = weight + (size_t)k * (CIN * COUT);
    bf16x8 bfrag[4][2];
#pragma unroll
    for (int t = 0; t < 4; ++t)
#pragma unroll
        for (int h = 0; h < 2; ++h) {
            const int n  = 16 * t + m;
            const int c0 = 32 * h + 8 * quad;
#pragma unroll
            for (int j = 0; j < 8; ++j)
                bfrag[t][h][j] = (short)f2bf(wk[(c0 + j) * COUT + n]);
        }

    const int base   = k * M;
    const int ntiles = M >> 4;   // 3125

    for (int tile = wave; tile < ntiles; tile += nwaves) {
        const int p0 = tile << 4;
        const int in_row = in_map[base + p0 + m];

        const float* __restrict__ fr = feats + (size_t)in_row * CIN + 8 * quad;
        const f32x4 f0 = *(const f32x4*)(fr + 0);
        const f32x4 f1 = *(const f32x4*)(fr + 4);
        const f32x4 f2 = *(const f32x4*)(fr + 32);
        const f32x4 f3 = *(const f32x4*)(fr + 36);

        bf16x8 a0, a1;
#pragma unroll
        for (int j = 0; j < 4; ++j) {
            a0[j]     = (short)f2bf(f0[j]);
            a0[j + 4] = (short)f2bf(f1[j]);
            a1[j]     = (short)f2bf(f2[j]);
            a1[j + 4] = (short)f2bf(f3[j]);
        }

        f32x4 acc[4];
#pragma unroll
        for (int t = 0; t < 4; ++t) {
            acc[t] = {0.f, 0.f, 0.f, 0.f};
            acc[t] = __builtin_amdgcn_mfma_f32_16x16x32_bf16(a0, bfrag[t][0], acc[t], 0, 0, 0);
            acc[t] = __builtin_amdgcn_mfma_f32_16x16x32_bf16(a1, bfrag[t][1], acc[t], 0, 0, 0);
        }

        // Store C in fragment-native layout (16 fp16 stores / lane / tile).
        const size_t tbase = ((size_t)(k * ntiles + tile) << 10) + 256 * quad + m;
#pragma unroll
        for (int t = 0; t < 4; ++t)
#pragma unroll
            for (int r = 0; r < 4; ++r)
                partial[tbase + 64 * r + 16 * t] = __float2half(acc[t][r]);
    }
}

// ---------------------------------------------------------------------------
// Phase 2: one wave per out row; gather <=CAP fp16 partial rows (128 B
// contiguous each), fp32-accumulate, write the fp32 row once. Writes every
// row -> no out-memset needed.
// ---------------------------------------------------------------------------
__global__ __launch_bounds__(256)
void spconv_phase2(const __half* __restrict__ partial,
                   const int*    __restrict__ cnt,
                   const int*    __restrict__ pairlist,
                   float*        __restrict__ out,
                   int nrows) {
    const int lane   = threadIdx.x & 63;
    const int wave   = blockIdx.x * 4 + (threadIdx.x >> 6);
    const int nwaves = gridDim.x * 4;

    for (int r = wave; r < nrows; r += nwaves) {
        int c = cnt[r];
        if (c > CAP) c = CAP;
        const int* __restrict__ pl = pairlist + r * CAP;

        float acc = 0.f;
        for (int j = 0; j < c; ++j) {
            const int e   = pl[j];              // wave-uniform scalar load
            const int r15 = e & 15;
            const size_t elem = ((size_t)(e >> 4) << 10)
                              + 256 * (r15 >> 2) + 64 * (r15 & 3) + lane;
            acc += __half2float(partial[elem]);
        }
        out[(size_t)r * COUT + lane] = acc;
    }
}

// ---------------------------------------------------------------------------
// Fallback (ws too small): round-2 kernel — scalar-atomic scatter, 283 us.
// ---------------------------------------------------------------------------
__global__ __launch_bounds__(256)
void spconv_atomic(const float* __restrict__ feats,
                   const float* __restrict__ weight,
                   const int*   __restrict__ in_map,
                   const int*   __restrict__ out_map,
                   float*       __restrict__ out,
                   int M) {
    const int k      = blockIdx.y;
    const int tid    = threadIdx.x;
    const int lane   = tid & 63;
    const int m      = lane & 15;
    const int quad   = lane >> 4;
    const int wave   = blockIdx.x * 4 + (tid >> 6);
    const int nwaves = gridDim.x * 4;

    const float* __restrict__ wk = weight + (size_t)k * (CIN * COUT);
    bf16x8 bfrag[4][2];
#pragma unroll
    for (int t = 0; t < 4; ++t)
#pragma unroll
        for (int h = 0; h < 2; ++h) {
            const int n  = 16 * t + m;
            const int c0 = 32 * h + 8 * quad;
#pragma unroll
            for (int j = 0; j < 8; ++j)
                bfrag[t][h][j] = (short)f2bf(wk[(c0 + j) * COUT + n]);
        }

    const int base   = k * M;
    const int ntiles = M >> 4;

    for (int tile = wave; tile < ntiles; tile += nwaves) {
        const int p0 = tile << 4;
        const int in_row  = in_map[base + p0 + m];
        const int out_row = out_map[base + p0 + m];

        const float* __restrict__ fr = feats + (size_t)in_row * CIN + 8 * quad;
        const f32x4 f0 = *(const f32x4*)(fr + 0);
        const f32x4 f1 = *(const f32x4*)(fr + 4);
        const f32x4 f2 = *(const f32x4*)(fr + 32);
        const f32x4 f3 = *(const f32x4*)(fr + 36);

        bf16x8 a0, a1;
#pragma unroll
        for (int j = 0; j < 4; ++j) {
            a0[j]     = (short)f2bf(f0[j]);
            a0[j + 4] = (short)f2bf(f1[j]);
            a1[j]     = (short)f2bf(f2[j]);
            a1[j + 4] = (short)f2bf(f3[j]);
        }

        int orow[4];
#pragma unroll
        for (int r = 0; r < 4; ++r)
            orow[r] = __shfl(out_row, 4 * quad + r);

        f32x4 acc[4];
#pragma unroll
        for (int t = 0; t < 4; ++t) {
            acc[t] = {0.f, 0.f, 0.f, 0.f};
            acc[t] = __builtin_amdgcn_mfma_f32_16x16x32_bf16(a0, bfrag[t][0], acc[t], 0, 0, 0);
            acc[t] = __builtin_amdgcn_mfma_f32_16x16x32_bf16(a1, bfrag[t][1], acc[t], 0, 0, 0);
        }

#pragma unroll
        for (int t = 0; t < 4; ++t)
#pragma unroll
            for (int r = 0; r < 4; ++r)
                atomicAdd(out + (size_t)orow[r] * COUT + 16 * t + m, acc[t][r]);
    }
}

__global__ __launch_bounds__(256)
void zero_out_kernel(float4* __restrict__ out, int n4) {
    int i = blockIdx.x * 256 + threadIdx.x;
    if (i < n4) out[i] = make_float4(0.f, 0.f, 0.f, 0.f);
}

extern "C" void kernel_launch(void* const* d_in, const int* in_sizes, int n_in,
                              void* d_out, int out_size, void* d_ws, size_t ws_size,
                              hipStream_t stream) {
    const float* feats   = (const float*)d_in[0];
    const float* weight  = (const float*)d_in[1];
    const int*   in_map  = (const int*)d_in[2];
    const int*   out_map = (const int*)d_in[3];
    float*       out     = (float*)d_out;

    const int K     = in_sizes[1] / (CIN * COUT);   // 27
    const int M     = in_sizes[2] / K;              // 50000
    const int N     = out_size / COUT;              // 200000
    const int total = K * M;                        // 1.35M

    // ws layout: cnt[N] | pairlist[N*CAP] | partial[total*64] fp16
    const size_t cnt_b  = ((size_t)N * 4 + 255) & ~(size_t)255;
    const size_t pl_b   = ((size_t)N * CAP * 4 + 255) & ~(size_t)255;
    const size_t part_b = (size_t)total * COUT * sizeof(__half);
    const size_t need   = cnt_b + pl_b + part_b;

    if ((M & 15) == 0 && ws_size >= need) {
        int*    cnt      = (int*)d_ws;
        int*    pairlist = (int*)((char*)d_ws + cnt_b);
        __half* partial  = (__half*)((char*)d_ws + cnt_b + pl_b);

        // counts must be zero every launch (ws re-poisoned to 0xAA)
        hipMemsetAsync(cnt, 0, (size_t)N * 4, stream);

        build_inverse<<<(total + 255) / 256, 256, 0, stream>>>(
            out_map, total, cnt, pairlist);

        dim3 g1(80, K);
        spconv_phase1<<<g1, 256, 0, stream>>>(feats, weight, in_map, partial, M);

        spconv_phase2<<<2048, 256, 0, stream>>>(partial, cnt, pairlist, out, N);
    } else {
        // Fallback: known-good atomic path.
        int n4 = out_size / 4;
        zero_out_kernel<<<(n4 + 255) / 256, 256, 0, stream>>>((float4*)out, n4);
        dim3 grid(80, K);
        spconv_atomic<<<grid, 256, 0, stream>>>(
            feats, weight, in_map, out_map, out, M);
    }
}

// Round 5
// 357.944 us; speedup vs baseline: 1.8197x; 1.4253x over previous
//
#include <hip/hip_runtime.h>
#include <hip/hip_fp16.h>

#define CIN   64
#define COUT  64
#define CAP   48   // per-out-row bucket capacity; counts ~Poisson(6.75), P(>=48)~1e-30

typedef __attribute__((ext_vector_type(8))) short bf16x8;
typedef __attribute__((ext_vector_type(4))) float f32x4;

// round-to-nearest-even f32 -> bf16 (bit pattern as ushort)
__device__ inline unsigned short f2bf(float f) {
    unsigned u = __float_as_uint(f);
    return (unsigned short)((u + 0x7FFFu + ((u >> 16) & 1u)) >> 16);
}

__device__ inline unsigned pack_h2(float lo, float hi) {
    __half l = __float2half(lo), h = __float2half(hi);
    return (unsigned)__half_as_ushort(l) | ((unsigned)__half_as_ushort(h) << 16);
}

// ---------------------------------------------------------------------------
// feats fp32 -> bf16 rows (one-time, 51.2 MB read / 25.6 MB write)
// ---------------------------------------------------------------------------
__global__ __launch_bounds__(256)
void cvt_feats(const float4* __restrict__ in, unsigned short* __restrict__ outb,
               int n8) {
    int i = blockIdx.x * 256 + threadIdx.x;
    if (i >= n8) return;
    float4 f0 = in[2 * i], f1 = in[2 * i + 1];
    bf16x8 o;
    o[0] = (short)f2bf(f0.x); o[1] = (short)f2bf(f0.y);
    o[2] = (short)f2bf(f0.z); o[3] = (short)f2bf(f0.w);
    o[4] = (short)f2bf(f1.x); o[5] = (short)f2bf(f1.y);
    o[6] = (short)f2bf(f1.z); o[7] = (short)f2bf(f1.w);
    *(bf16x8*)(outb + 8 * (size_t)i) = o;
}

// ---------------------------------------------------------------------------
// Inverse rulebook: per out row, list of global pair ids g = k*M + p.
// ---------------------------------------------------------------------------
__global__ __launch_bounds__(256)
void build_inverse(const int* __restrict__ out_map, int total,
                   int* __restrict__ cnt, int* __restrict__ pairlist) {
    int g = blockIdx.x * 256 + threadIdx.x;
    if (g >= total) return;
    int r = out_map[g];
    int pos = atomicAdd(&cnt[r], 1);
    if (pos < CAP) pairlist[r * CAP + pos] = g;
}

// ---------------------------------------------------------------------------
// Phase 1: implicit-GEMM (MFMA), partial[g][64] fp16 ROW-MAJOR via paired
// half2 stores (8 dword stores / lane / tile). Template: PRE -> gather from
// pre-converted bf16 feats (2x16B loads, no cvt in loop).
// ---------------------------------------------------------------------------
template <bool PRE>
__global__ __launch_bounds__(256)
void spconv_phase1(const float*          __restrict__ feats,
                   const unsigned short* __restrict__ featsb,
                   const float*          __restrict__ weight,
                   const int*            __restrict__ in_map,
                   unsigned*             __restrict__ partial_dw,
                   int M) {
    const int k      = blockIdx.y;
    const int tid    = threadIdx.x;
    const int lane   = tid & 63;
    const int m      = lane & 15;
    const int quad   = lane >> 4;
    const int wave   = blockIdx.x * 4 + (tid >> 6);
    const int nwaves = gridDim.x * 4;
    const bool odd   = (m & 1);

    // Preload B fragments: b[t][h][j] = W[k][32h+8q+j][16t+m]
    const float* __restrict__ wk = weight + (size_t)k * (CIN * COUT);
    bf16x8 bfrag[4][2];
#pragma unroll
    for (int t = 0; t < 4; ++t)
#pragma unroll
        for (int h = 0; h < 2; ++h) {
            const int n  = 16 * t + m;
            const int c0 = 32 * h + 8 * quad;
#pragma unroll
            for (int j = 0; j < 8; ++j)
                bfrag[t][h][j] = (short)f2bf(wk[(c0 + j) * COUT + n]);
        }

    const int base   = k * M;
    const int ntiles = M >> 4;   // 3125

    for (int tile = wave; tile < ntiles; tile += nwaves) {
        const int p0     = tile << 4;
        const int in_row = in_map[base + p0 + m];

        bf16x8 a0, a1;
        if (PRE) {
            const unsigned short* fb = featsb + ((size_t)in_row << 6) + 8 * quad;
            a0 = *(const bf16x8*)fb;          // channels [8q, 8q+8)
            a1 = *(const bf16x8*)(fb + 32);   // channels [8q+32, 8q+40)
        } else {
            const float* __restrict__ fr = feats + ((size_t)in_row << 6) + 8 * quad;
            const f32x4 f0 = *(const f32x4*)(fr + 0);
            const f32x4 f1 = *(const f32x4*)(fr + 4);
            const f32x4 f2 = *(const f32x4*)(fr + 32);
            const f32x4 f3 = *(const f32x4*)(fr + 36);
#pragma unroll
            for (int j = 0; j < 4; ++j) {
                a0[j]     = (short)f2bf(f0[j]);
                a0[j + 4] = (short)f2bf(f1[j]);
                a1[j]     = (short)f2bf(f2[j]);
                a1[j + 4] = (short)f2bf(f3[j]);
            }
        }

        f32x4 acc[4];
#pragma unroll
        for (int t = 0; t < 4; ++t) {
            acc[t] = {0.f, 0.f, 0.f, 0.f};
            acc[t] = __builtin_amdgcn_mfma_f32_16x16x32_bf16(a0, bfrag[t][0], acc[t], 0, 0, 0);
            acc[t] = __builtin_amdgcn_mfma_f32_16x16x32_bf16(a1, bfrag[t][1], acc[t], 0, 0, 0);
        }

        // Epilogue: pair cols (m, m^1) via shfl_xor(1); even lane writes rows
        // 4q+{0,1}, odd lane rows 4q+{2,3}; half2 dword stores, row-major.
        const int g0    = base + p0;
        const int coldw = 8 * 0 + (m >> 1);  // + 8t added per t below
        const int row0  = 4 * quad + (odd ? 2 : 0);
#pragma unroll
        for (int t = 0; t < 4; ++t) {
            const float send0 = odd ? acc[t][0] : acc[t][2];
            const float send1 = odd ? acc[t][1] : acc[t][3];
            const float recv0 = __shfl_xor(send0, 1);
            const float recv1 = __shfl_xor(send1, 1);

            const unsigned d0 = odd ? pack_h2(recv0, acc[t][2])
                                    : pack_h2(acc[t][0], recv0);
            const unsigned d1 = odd ? pack_h2(recv1, acc[t][3])
                                    : pack_h2(acc[t][1], recv1);

            partial_dw[(size_t)(g0 + row0)     * 32 + coldw + 8 * t] = d0;
            partial_dw[(size_t)(g0 + row0 + 1) * 32 + coldw + 8 * t] = d1;
        }
    }
}

// ---------------------------------------------------------------------------
// Phase 2: one wave per out row. Lane reads a dword (2 cols) so 32 lanes
// cover one entry (128 B coalesced); 2 entries/step, 4 loads in flight.
// ---------------------------------------------------------------------------
__global__ __launch_bounds__(256)
void spconv_phase2(const unsigned* __restrict__ partial_dw,
                   const int*      __restrict__ cnt,
                   const int*      __restrict__ pairlist,
                   float*          __restrict__ out,
                   int nrows) {
    const int tid   = threadIdx.x;
    const int lane  = tid & 63;
    const int half  = lane >> 5;
    const int c2    = lane & 31;
    const int wave  = blockIdx.x * 4 + (tid >> 6);
    const int nw    = gridDim.x * 4;

    for (int r = wave; r < nrows; r += nw) {
        int c = cnt[r];
        if (c > CAP) c = CAP;

        int pe = 0;
        if (lane < CAP) pe = pairlist[r * CAP + lane];

        float ax = 0.f, ay = 0.f;
        for (int j0 = 0; j0 < c; j0 += 8) {
            unsigned v[4];
            bool     vl[4];
#pragma unroll
            for (int u = 0; u < 4; ++u) {
                const int slot = j0 + 2 * u + half;
                const int e    = __shfl(pe, slot);
                vl[u] = (slot < c);
                const size_t idx = ((size_t)(vl[u] ? e : 0) << 5) + c2;
                v[u] = partial_dw[idx];
            }
#pragma unroll
            for (int u = 0; u < 4; ++u) {
                const float lo = __half2float(__ushort_as_half((unsigned short)(v[u] & 0xFFFF)));
                const float hi = __half2float(__ushort_as_half((unsigned short)(v[u] >> 16)));
                if (vl[u]) { ax += lo; ay += hi; }
            }
        }

        // combine even/odd-slot halves, then 256 B coalesced float2 store
        ax += __shfl_xor(ax, 32);
        ay += __shfl_xor(ay, 32);
        if (half == 0)
            ((float2*)out)[(size_t)r * 32 + c2] = make_float2(ax, ay);
    }
}

// ---------------------------------------------------------------------------
// Fallback (ws too small): round-2 atomic kernel (known-good, ~283 us).
// ---------------------------------------------------------------------------
__global__ __launch_bounds__(256)
void spconv_atomic(const float* __restrict__ feats,
                   const float* __restrict__ weight,
                   const int*   __restrict__ in_map,
                   const int*   __restrict__ out_map,
                   float*       __restrict__ out,
                   int M) {
    const int k      = blockIdx.y;
    const int tid    = threadIdx.x;
    const int lane   = tid & 63;
    const int m      = lane & 15;
    const int quad   = lane >> 4;
    const int wave   = blockIdx.x * 4 + (tid >> 6);
    const int nwaves = gridDim.x * 4;

    const float* __restrict__ wk = weight + (size_t)k * (CIN * COUT);
    bf16x8 bfrag[4][2];
#pragma unroll
    for (int t = 0; t < 4; ++t)
#pragma unroll
        for (int h = 0; h < 2; ++h) {
            const int n  = 16 * t + m;
            const int c0 = 32 * h + 8 * quad;
#pragma unroll
            for (int j = 0; j < 8; ++j)
                bfrag[t][h][j] = (short)f2bf(wk[(c0 + j) * COUT + n]);
        }

    const int base   = k * M;
    const int ntiles = M >> 4;

    for (int tile = wave; tile < ntiles; tile += nwaves) {
        const int p0 = tile << 4;
        const int in_row  = in_map[base + p0 + m];
        const int out_row = out_map[base + p0 + m];

        const float* __restrict__ fr = feats + ((size_t)in_row << 6) + 8 * quad;
        const f32x4 f0 = *(const f32x4*)(fr + 0);
        const f32x4 f1 = *(const f32x4*)(fr + 4);
        const f32x4 f2 = *(const f32x4*)(fr + 32);
        const f32x4 f3 = *(const f32x4*)(fr + 36);

        bf16x8 a0, a1;
#pragma unroll
        for (int j = 0; j < 4; ++j) {
            a0[j]     = (short)f2bf(f0[j]);
            a0[j + 4] = (short)f2bf(f1[j]);
            a1[j]     = (short)f2bf(f2[j]);
            a1[j + 4] = (short)f2bf(f3[j]);
        }

        int orow[4];
#pragma unroll
        for (int r = 0; r < 4; ++r)
            orow[r] = __shfl(out_row, 4 * quad + r);

        f32x4 acc[4];
#pragma unroll
        for (int t = 0; t < 4; ++t) {
            acc[t] = {0.f, 0.f, 0.f, 0.f};
            acc[t] = __builtin_amdgcn_mfma_f32_16x16x32_bf16(a0, bfrag[t][0], acc[t], 0, 0, 0);
            acc[t] = __builtin_amdgcn_mfma_f32_16x16x32_bf16(a1, bfrag[t][1], acc[t], 0, 0, 0);
        }

#pragma unroll
        for (int t = 0; t < 4; ++t)
#pragma unroll
            for (int r = 0; r < 4; ++r)
                atomicAdd(out + (size_t)orow[r] * COUT + 16 * t + m, acc[t][r]);
    }
}

__global__ __launch_bounds__(256)
void zero_out_kernel(float4* __restrict__ out, int n4) {
    int i = blockIdx.x * 256 + threadIdx.x;
    if (i < n4) out[i] = make_float4(0.f, 0.f, 0.f, 0.f);
}

extern "C" void kernel_launch(void* const* d_in, const int* in_sizes, int n_in,
                              void* d_out, int out_size, void* d_ws, size_t ws_size,
                              hipStream_t stream) {
    const float* feats   = (const float*)d_in[0];
    const float* weight  = (const float*)d_in[1];
    const int*   in_map  = (const int*)d_in[2];
    const int*   out_map = (const int*)d_in[3];
    float*       out     = (float*)d_out;

    const int K     = in_sizes[1] / (CIN * COUT);   // 27
    const int M     = in_sizes[2] / K;              // 50000
    const int N     = out_size / COUT;              // 200000
    const int total = K * M;                        // 1.35M

    // ws layout: cnt[N] | pairlist[N*CAP] | partial[total*64] fp16 | featsb
    const size_t cnt_b  = ((size_t)N * 4 + 255) & ~(size_t)255;
    const size_t pl_b   = ((size_t)N * CAP * 4 + 255) & ~(size_t)255;
    const size_t part_b = ((size_t)total * COUT * 2 + 255) & ~(size_t)255;
    const size_t fb_b   = (size_t)N * CIN * 2;
    const size_t need_small = cnt_b + pl_b + part_b;
    const size_t need_big   = need_small + fb_b;

    if ((M & 15) == 0 && ws_size >= need_small) {
        int*      cnt      = (int*)d_ws;
        int*      pairlist = (int*)((char*)d_ws + cnt_b);
        unsigned* partial  = (unsigned*)((char*)d_ws + cnt_b + pl_b);

        hipMemsetAsync(cnt, 0, (size_t)N * 4, stream);
        build_inverse<<<(total + 255) / 256, 256, 0, stream>>>(
            out_map, total, cnt, pairlist);

        dim3 g1(80, K);
        if (ws_size >= need_big) {
            unsigned short* featsb = (unsigned short*)((char*)d_ws + need_small);
            const int n8 = N * CIN / 8;
            cvt_feats<<<(n8 + 255) / 256, 256, 0, stream>>>(
                (const float4*)feats, featsb, n8);
            spconv_phase1<true><<<g1, 256, 0, stream>>>(
                feats, featsb, weight, in_map, partial, M);
        } else {
            spconv_phase1<false><<<g1, 256, 0, stream>>>(
                feats, nullptr, weight, in_map, partial, M);
        }

        spconv_phase2<<<4096, 256, 0, stream>>>(partial, cnt, pairlist, out, N);
    } else {
        int n4 = out_size / 4;
        zero_out_kernel<<<(n4 + 255) / 256, 256, 0, stream>>>((float4*)out, n4);
        dim3 grid(80, K);
        spconv_atomic<<<grid, 256, 0, stream>>>(
            feats, weight, in_map, out_map, out, M);
    }
}